// Round 3
// baseline (331.806 us; speedup 1.0000x reference)
//
#include <hip/hip_runtime.h>
#include <math.h>

#define Bq 4
#define Hq 512
#define Nq 64
#define Lq 2048
#define PARAM (Hq*Nq)   // 32768
#define T 64
#define NC (Lq/T)       // 32 chunks
#define NCOL 256        // 2 dirs * Bq * NC columns per h

// ---------------------------------------------------------------------------
// Phase 1: per-(h,n) parameter prep + global power table.
//   w = exp(dt*A);  dB = B*(w-1)/A;  CB = C*dB
//   a = 2*Re(CB), b = -2*Im(CB)  (so y += a*sr + b*si)
//   pw[h][d][n] = (Re w^d, Im w^d) for d = 0..64, float2 interleaved.
// ---------------------------------------------------------------------------
__global__ void prep_kernel(const float* __restrict__ log_dt,
                            const float* __restrict__ log_A_real,
                            const float* __restrict__ A_imag,
                            const float* __restrict__ B_re, const float* __restrict__ B_im,
                            const float* __restrict__ C_re, const float* __restrict__ C_im,
                            float* __restrict__ a0, float* __restrict__ b0,
                            float* __restrict__ a1, float* __restrict__ b1,
                            float* __restrict__ pw) {
    int idx = blockIdx.x * blockDim.x + threadIdx.x;
    if (idx >= PARAM) return;
    int h = idx >> 6, n = idx & 63;
    float dt = expf(log_dt[h]);
    float Ar = -expf(log_A_real[idx]);
    float Ai = A_imag[idx];
    float er = expf(Ar * dt);
    float wr = er * cosf(Ai * dt);
    float wi = er * sinf(Ai * dt);
    float mr = wr - 1.0f, mi = wi;
    float den = Ar * Ar + Ai * Ai;
    float qr = (mr * Ar + mi * Ai) / den;
    float qi = (mi * Ar - mr * Ai) / den;
    float Br = B_re[idx], Bi = B_im[idx];
    float dBr = Br * qr - Bi * qi;
    float dBi = Br * qi + Bi * qr;
    float cr = C_re[idx], ci = C_im[idx];
    a0[idx] =  2.0f * (cr * dBr - ci * dBi);
    b0[idx] = -2.0f * (cr * dBi + ci * dBr);
    cr = C_re[PARAM + idx]; ci = C_im[PARAM + idx];
    a1[idx] =  2.0f * (cr * dBr - ci * dBi);
    b1[idx] = -2.0f * (cr * dBi + ci * dBr);
    // power chain w^0 .. w^64 (coalesced float2 writes across n)
    float c = 1.f, s = 0.f;
    float* base = pw + (size_t)h * 65 * 128 + 2 * n;
    for (int d = 0; d <= 64; ++d) {
        *(float2*)(base + (size_t)d * 128) = float2{c, s};
        float nc = c * wr - s * wi;
        float ns = c * wi + s * wr;
        c = nc; s = ns;
    }
}

// ---------------------------------------------------------------------------
// Phase 1b: Toeplitz taps k[h][dir][d] = sum_n a*Re(w^d) + b*Im(w^d).
// (dir1's lag shift is handled at Toeplitz-build: tap for lag L is k[L-1].)
// ---------------------------------------------------------------------------
__global__ __launch_bounds__(128)
void ktap_kernel(const float* __restrict__ pw,
                 const float* __restrict__ a0, const float* __restrict__ b0,
                 const float* __restrict__ a1, const float* __restrict__ b1,
                 float* __restrict__ kt) {
    int h = blockIdx.x;
    int t = threadIdx.x;
    int dir = t >> 6, d = t & 63;
    const float* aa = dir ? a1 : a0;
    const float* bb = dir ? b1 : b0;
    const float* row = pw + (size_t)(h * 65 + d) * 128;
    float acc = 0.f;
    for (int n = 0; n < 64; ++n) {
        float2 v = *(const float2*)(row + 2 * n);
        acc = fmaf(aa[h * 64 + n], v.x, acc);
        acc = fmaf(bb[h * 64 + n], v.y, acc);
    }
    kt[((size_t)h * 2 + dir) * 64 + d] = acc;
}

// ---------------------------------------------------------------------------
// Phase 2: LayerNorm over channel dim H for each (b,l).  (unchanged)
// ---------------------------------------------------------------------------
__global__ __launch_bounds__(256)
void ln_kernel(const float* __restrict__ x, const float* __restrict__ lnw,
               const float* __restrict__ lnb, float* __restrict__ z) {
    int blk = blockIdx.x;
    int b  = blk / (Lq / 16);
    int l0 = (blk % (Lq / 16)) * 16;
    int tx = threadIdx.x & 15;
    int ty = threadIdx.x >> 4;
    const float* xb = x + (size_t)b * Hq * Lq;
    float s = 0.f, s2 = 0.f;
    for (int h = ty; h < Hq; h += 16) {
        float v = xb[h * Lq + l0 + tx];
        s += v; s2 += v * v;
    }
    __shared__ float rs_[16][17], r2_[16][17], mu_s[16], sg_s[16];
    rs_[ty][tx] = s; r2_[ty][tx] = s2;
    __syncthreads();
    if (ty == 0) {
        float a = 0.f, c = 0.f;
        #pragma unroll
        for (int i = 0; i < 16; ++i) { a += rs_[i][tx]; c += r2_[i][tx]; }
        float mu = a * (1.0f / Hq);
        float var = c * (1.0f / Hq) - mu * mu;
        mu_s[tx] = mu;
        sg_s[tx] = rsqrtf(var + 1e-5f);
    }
    __syncthreads();
    float mu = mu_s[tx], rs = sg_s[tx];
    float* zb = z + (size_t)b * Hq * Lq;
    for (int h = ty; h < Hq; h += 16) {
        float v = xb[h * Lq + l0 + tx];
        zb[h * Lq + l0 + tx] = (v - mu) * rs * lnw[h] + lnb[h];
    }
}

// ---------------------------------------------------------------------------
// SSD decomposition. tau: dir0 -> z[tau], dir1 -> z[L-1-tau].
// Chunk c covers tau in [c*64, c*64+64). zhat[c,j] = z[scan(c*64+j)].
// col = dir*128 + b*32 + c everywhere.
// delta[n] = sum_j w^(63-j) zhat[j]; buf[h][col][2n,2n+1] = (Re,Im).
// ---------------------------------------------------------------------------

// delta GEMM: per (h, ct): rows 2n/2n+1 = 128, cols 64, K = 64.
// A-operand (w powers) read straight from the L2-resident global table.
__global__ __launch_bounds__(256, 6)
void delta_kernel(const float* __restrict__ z, const float* __restrict__ pw,
                  float* __restrict__ buf) {
    __shared__ float Bs[64][68];          // [j][col-local], writes lane-along-col
    int h = blockIdx.x, ct = blockIdx.y;  // dir = ct>>1, b-pair = ct&1
    int t = threadIdx.x;
    int dir = ct >> 1;
    int cc = t & 31, rb = (t >> 5) & 1, jg = t >> 6;   // j0 = 16*jg
    int b = (ct & 1) * 2 + rb;
    const float* zb = z + ((size_t)b * Hq + h) * Lq;
    if (dir == 0) {
        #pragma unroll
        for (int f = 0; f < 4; ++f) {
            float4 v = *(const float4*)(zb + cc * 64 + 16 * jg + 4 * f);
            Bs[16*jg+4*f+0][rb*32+cc] = v.x;
            Bs[16*jg+4*f+1][rb*32+cc] = v.y;
            Bs[16*jg+4*f+2][rb*32+cc] = v.z;
            Bs[16*jg+4*f+3][rb*32+cc] = v.w;
        }
    } else {
        #pragma unroll
        for (int f = 0; f < 4; ++f) {
            float4 v = *(const float4*)(zb + 2044 - cc * 64 - 16 * jg - 4 * f);
            Bs[16*jg+4*f+3][rb*32+cc] = v.x;
            Bs[16*jg+4*f+2][rb*32+cc] = v.y;
            Bs[16*jg+4*f+1][rb*32+cc] = v.z;
            Bs[16*jg+4*f+0][rb*32+cc] = v.w;
        }
    }
    __syncthreads();
    int tx = t & 15, ty = t >> 4;
    float aR[4][4] = {}, aI[4][4] = {};
    const float* pwh = pw + (size_t)h * 65 * 128;
    #pragma unroll 4
    for (int kk = 0; kk < 64; ++kk) {
        int d = 63 - kk;
        const float4* pr = (const float4*)(pwh + (size_t)d * 128 + 8 * tx);
        float4 p0 = pr[0], p1 = pr[1];    // (re,im,re,im) n=4tx..4tx+3
        float4 bv = *(const float4*)&Bs[kk][4 * ty];
        float pc[4] = {p0.x, p0.z, p1.x, p1.z};
        float ps[4] = {p0.y, p0.w, p1.y, p1.w};
        #pragma unroll
        for (int rr = 0; rr < 4; ++rr) {
            #pragma unroll
            for (int q = 0; q < 4; ++q) {
                aR[rr][q] = fmaf(pc[rr], (&bv.x)[q], aR[rr][q]);
                aI[rr][q] = fmaf(ps[rr], (&bv.x)[q], aI[rr][q]);
            }
        }
    }
    #pragma unroll
    for (int q = 0; q < 4; ++q) {
        int colg = ct * 64 + 4 * ty + q;
        float* dst = buf + ((size_t)h * NCOL + colg) * 128 + 8 * tx;
        float4 v1, v2;
        v1.x = aR[0][q]; v1.y = aI[0][q]; v1.z = aR[1][q]; v1.w = aI[1][q];
        v2.x = aR[2][q]; v2.y = aI[2][q]; v2.z = aR[3][q]; v2.w = aI[3][q];
        *(float4*)dst = v1; *(float4*)(dst + 4) = v2;
    }
}

// inter-chunk scan, in place: reads delta[c], writes s_init[c] (pre-state).
__global__ __launch_bounds__(256)
void cscan_kernel(const float* __restrict__ pw, float* __restrict__ buf) {
    int e = blockIdx.x * 4 + (threadIdx.x >> 6);    // h*8 + dir*4 + b
    int n = threadIdx.x & 63;
    int h = e >> 3, dir = (e >> 2) & 1, b = e & 3;
    float2 t64 = *(const float2*)(pw + (size_t)(h * 65 + 64) * 128 + 2 * n);
    float tc = t64.x, ts = t64.y;
    float sr = 0.f, si = 0.f;
    float2* p = (float2*)(buf + ((size_t)h * NCOL + dir * 128 + b * 32) * 128) + n;
    float2 d = p[0];
    for (int c = 0; c < NC; ++c) {
        float2 dn;
        if (c + 1 < NC) dn = p[(c + 1) * 64];
        float2 s; s.x = sr; s.y = si;
        p[c * 64] = s;
        float nr = fmaf(tc, sr, fmaf(-ts, si, d.x));
        float ni = fmaf(ts, sr, fmaf(tc, si, d.y));
        sr = nr; si = ni; d = dn;
    }
}

// Y GEMM: per (h, dir, ct): Y[64 rows][64 cols] = K_toeplitz@zhat + G@S, K=192.
// As/Bs both [kk][*], all LDS accesses conflict-free (<=2-way).
__global__ __launch_bounds__(256, 8)
void y_kernel(const float* __restrict__ z, const float* __restrict__ pw,
              const float* __restrict__ a0, const float* __restrict__ b0,
              const float* __restrict__ a1, const float* __restrict__ b1,
              const float* __restrict__ kt, const float* __restrict__ buf,
              float* __restrict__ y0, float* __restrict__ y1) {
    __shared__ float As[32][68];
    __shared__ float Bs[32][68];
    __shared__ float ks[64], as_[64], bs_[64];
    int h = blockIdx.x, dir = blockIdx.y, ct = blockIdx.z;
    int t = threadIdx.x;
    if (t < 64) {
        ks[t]  = kt[((size_t)h * 2 + dir) * 64 + t];
        as_[t] = (dir ? a1 : a0)[h * 64 + t];
        bs_[t] = (dir ? b1 : b0)[h * 64 + t];
    }
    int tx = t & 15, ty = t >> 4;
    int si = t & 63, sg = t >> 6;                    // As staging: row i=si
    int cc = t & 31, rb = (t >> 5) & 1, kg = t >> 6; // Bs staging
    int b = ct * 2 + rb;
    const float* zb = z + ((size_t)b * Hq + h) * Lq;
    int off = (dir == 0) ? 1 : 0;
    const float* prow = pw + (size_t)(h * 65 + si + off) * 128;
    float acc[4][4] = {};
    __syncthreads();
    for (int p = 0; p < 6; ++p) {
        // ---- stage As[kk][i] ----
        if (p < 2) {
            #pragma unroll
            for (int q = 0; q < 8; ++q) {
                int kk = 8 * sg + q;
                int j = 32 * p + kk;
                int idx = (dir == 0) ? (si - j) : (si - j - 1);
                As[kk][si] = (idx >= 0) ? ks[idx] : 0.f;
            }
        } else {
            #pragma unroll
            for (int q = 0; q < 8; ++q) {
                int kk = 8 * sg + q;
                int m = 32 * (p - 2) + kk;
                int n = m >> 1;
                float2 v = *(const float2*)(prow + 2 * n);
                float av = as_[n], bv = bs_[n];
                As[kk][si] = ((m & 1) == 0) ? fmaf(av, v.x, bv * v.y)
                                            : fmaf(bv, v.x, -av * v.y);
            }
        }
        // ---- stage Bs[kk][col] ----
        if (p < 2) {
            if (dir == 0) {
                #pragma unroll
                for (int f = 0; f < 2; ++f) {
                    float4 v = *(const float4*)(zb + cc * 64 + 32 * p + 8 * kg + 4 * f);
                    Bs[8*kg+4*f+0][rb*32+cc] = v.x;
                    Bs[8*kg+4*f+1][rb*32+cc] = v.y;
                    Bs[8*kg+4*f+2][rb*32+cc] = v.z;
                    Bs[8*kg+4*f+3][rb*32+cc] = v.w;
                }
            } else {
                #pragma unroll
                for (int f = 0; f < 2; ++f) {
                    float4 v = *(const float4*)(zb + 2044 - cc * 64 - 32 * p - 8 * kg - 4 * f);
                    Bs[8*kg+4*f+3][rb*32+cc] = v.x;
                    Bs[8*kg+4*f+2][rb*32+cc] = v.y;
                    Bs[8*kg+4*f+1][rb*32+cc] = v.z;
                    Bs[8*kg+4*f+0][rb*32+cc] = v.w;
                }
            }
        } else {
            int colg = dir * 128 + ct * 64 + rb * 32 + cc;
            const float* src = buf + ((size_t)h * NCOL + colg) * 128 + 32 * (p - 2) + 8 * kg;
            float4 v0 = *(const float4*)src;
            float4 v1 = *(const float4*)(src + 4);
            #pragma unroll
            for (int e2 = 0; e2 < 4; ++e2) Bs[8*kg+e2][rb*32+cc]   = (&v0.x)[e2];
            #pragma unroll
            for (int e2 = 0; e2 < 4; ++e2) Bs[8*kg+4+e2][rb*32+cc] = (&v1.x)[e2];
        }
        __syncthreads();
        #pragma unroll 8
        for (int kk = 0; kk < 32; ++kk) {
            float4 av = *(const float4*)&As[kk][4 * tx];
            float4 bv = *(const float4*)&Bs[kk][4 * ty];
            #pragma unroll
            for (int ii = 0; ii < 4; ++ii) {
                float a = (&av.x)[ii];
                acc[ii][0] = fmaf(a, bv.x, acc[ii][0]);
                acc[ii][1] = fmaf(a, bv.y, acc[ii][1]);
                acc[ii][2] = fmaf(a, bv.z, acc[ii][2]);
                acc[ii][3] = fmaf(a, bv.w, acc[ii][3]);
            }
        }
        __syncthreads();
    }
    #pragma unroll
    for (int q = 0; q < 4; ++q) {
        int coll = 4 * ty + q;
        int bo = ct * 2 + (coll >> 5), c = coll & 31;
        float4 v;
        if (dir == 0) {
            v.x = acc[0][q]; v.y = acc[1][q]; v.z = acc[2][q]; v.w = acc[3][q];
            *(float4*)(y0 + ((size_t)bo * Hq + h) * Lq + c * 64 + 4 * tx) = v;
        } else {
            v.x = acc[3][q]; v.y = acc[2][q]; v.z = acc[1][q]; v.w = acc[0][q];
            *(float4*)(y1 + ((size_t)bo * Hq + h) * Lq + 2044 - c * 64 - 4 * tx) = v;
        }
    }
}

// ---------------------------------------------------------------------------
// Phase 4: u = gelu_tanh(y0 + y1 + D*z), in-place into y0. (unchanged)
// ---------------------------------------------------------------------------
__global__ __launch_bounds__(256)
void act_kernel(float4* __restrict__ y0, const float4* __restrict__ y1,
                const float4* __restrict__ z, const float* __restrict__ D) {
    int i4 = blockIdx.x * 256 + threadIdx.x;
    int h = (i4 >> 9) & (Hq - 1);
    float d = D[h];
    float4 v0 = y0[i4], v1 = y1[i4], vz = z[i4];
    float vv[4] = { v0.x + v1.x + d * vz.x, v0.y + v1.y + d * vz.y,
                    v0.z + v1.z + d * vz.z, v0.w + v1.w + d * vz.w };
    #pragma unroll
    for (int i = 0; i < 4; ++i) {
        float v = vv[i];
        float tt = tanhf(0.7978845608028654f * (v + 0.044715f * v * v * v));
        vv[i] = 0.5f * v * (1.0f + tt);
    }
    float4 r; r.x = vv[0]; r.y = vv[1]; r.z = vv[2]; r.w = vv[3];
    y0[i4] = r;
}

// ---------------------------------------------------------------------------
// Phase 5: out = bias + x + W@u. (unchanged)
// ---------------------------------------------------------------------------
__global__ __launch_bounds__(256)
void gemm_kernel(const float* __restrict__ u, const float* __restrict__ W,
                 const float* __restrict__ bias, const float* __restrict__ x,
                 float* __restrict__ out) {
    int l0 = blockIdx.x * 64;
    int o0 = blockIdx.y * 128;
    int b  = blockIdx.z;
    int tid = threadIdx.x;
    __shared__ float Ws[16][129];
    __shared__ float Us[16][65];
    const float* ub = u + (size_t)b * Hq * Lq;
    float acc[8][4] = {};
    int wo = tid >> 4, wl = tid & 15;
    for (int k0 = 0; k0 < Hq; k0 += 16) {
        {
            int j  = tid & 15;
            int ib = tid >> 4;
            #pragma unroll
            for (int r = 0; r < 8; ++r) {
                int i = ib + 16 * r;
                Ws[j][i] = W[(size_t)(o0 + i) * Hq + k0 + j];
            }
            int li = tid & 63;
            int jb = tid >> 6;
            #pragma unroll
            for (int r = 0; r < 4; ++r) {
                int j2 = jb + 4 * r;
                Us[j2][li] = ub[(size_t)(k0 + j2) * Lq + l0 + li];
            }
        }
        __syncthreads();
        #pragma unroll
        for (int j = 0; j < 16; ++j) {
            float av[8], bv[4];
            #pragma unroll
            for (int i = 0; i < 8; ++i) av[i] = Ws[j][8 * wo + i];
            #pragma unroll
            for (int i = 0; i < 4; ++i) bv[i] = Us[j][4 * wl + i];
            #pragma unroll
            for (int io = 0; io < 8; ++io)
                #pragma unroll
                for (int il = 0; il < 4; ++il)
                    acc[io][il] = fmaf(av[io], bv[il], acc[io][il]);
        }
        __syncthreads();
    }
    #pragma unroll
    for (int io = 0; io < 8; ++io) {
        int o = o0 + 8 * wo + io;
        float bo = bias[o];
        size_t base = ((size_t)b * Hq + o) * Lq + l0 + 4 * wl;
        const float4 xr = *(const float4*)(x + base);
        float4 r;
        r.x = acc[io][0] + bo + xr.x;
        r.y = acc[io][1] + bo + xr.y;
        r.z = acc[io][2] + bo + xr.z;
        r.w = acc[io][3] + bo + xr.w;
        *(float4*)(out + base) = r;
    }
}

// ---------------------------------------------------------------------------
extern "C" void kernel_launch(void* const* d_in, const int* in_sizes, int n_in,
                              void* d_out, int out_size, void* d_ws, size_t ws_size,
                              hipStream_t stream) {
    (void)in_sizes; (void)n_in; (void)out_size; (void)ws_size;
    const float* x          = (const float*)d_in[0];
    const float* ln_w       = (const float*)d_in[1];
    const float* ln_b       = (const float*)d_in[2];
    const float* log_dt     = (const float*)d_in[3];
    const float* log_A_real = (const float*)d_in[4];
    const float* A_imag     = (const float*)d_in[5];
    const float* B_re       = (const float*)d_in[6];
    const float* B_im       = (const float*)d_in[7];
    const float* C_re       = (const float*)d_in[8];
    const float* C_im       = (const float*)d_in[9];
    const float* Dv         = (const float*)d_in[10];
    const float* W          = (const float*)d_in[11];
    const float* b_out      = (const float*)d_in[12];
    float* out = (float*)d_out;
    float* ws  = (float*)d_ws;

    const size_t BHL = (size_t)Bq * Hq * Lq;       // 4,194,304 = 128*PARAM
    float* a0  = ws;
    float* b0  = ws + (size_t)PARAM;
    float* a1  = ws + 2 * (size_t)PARAM;
    float* b1  = ws + 3 * (size_t)PARAM;
    float* kt  = ws + 4 * (size_t)PARAM;           // 2*Hq*64 = 2*PARAM
    float* pw  = ws + 6 * (size_t)PARAM;           // 512*65*128 = 130*PARAM
    float* z   = ws + 136 * (size_t)PARAM;
    float* y0  = z  + BHL;
    float* y1  = y0 + BHL;
    float* buf = y1 + BHL;                         // 512*256*128 = 67 MB

    prep_kernel<<<PARAM / 256, 256, 0, stream>>>(log_dt, log_A_real, A_imag,
                                                 B_re, B_im, C_re, C_im,
                                                 a0, b0, a1, b1, pw);
    ln_kernel<<<Bq * (Lq / 16), 256, 0, stream>>>(x, ln_w, ln_b, z);
    ktap_kernel<<<Hq, 128, 0, stream>>>(pw, a0, b0, a1, b1, kt);
    delta_kernel<<<dim3(Hq, 4), 256, 0, stream>>>(z, pw, buf);
    cscan_kernel<<<Bq * Hq * 2 / 4, 256, 0, stream>>>(pw, buf);
    y_kernel<<<dim3(Hq, 2, 2), 256, 0, stream>>>(z, pw, a0, b0, a1, b1,
                                                 kt, buf, y0, y1);
    act_kernel<<<(Bq * Hq * Lq / 4) / 256, 256, 0, stream>>>((float4*)y0, (const float4*)y1,
                                                             (const float4*)z, Dv);
    gemm_kernel<<<dim3(Lq / 64, Hq / 128, Bq), 256, 0, stream>>>(y0, W, b_out, x, out);
}

// Round 4
// 308.310 us; speedup vs baseline: 1.0762x; 1.0762x over previous
//
#include <hip/hip_runtime.h>
#include <math.h>

#define Bq 4
#define Hq 512
#define Nq 64
#define Lq 2048
#define PARAM (Hq*Nq)   // 32768
#define T 64
#define NC (Lq/T)       // 32 chunks
#define NCOL 256        // 2 dirs * Bq * NC columns per h

// ---------------------------------------------------------------------------
// Phase 1: per-(h,n) parameter prep + global power table.
//   pw[h][d][n] = (Re w^d, Im w^d) for d = 0..64, float2 interleaved.
// ---------------------------------------------------------------------------
__global__ void prep_kernel(const float* __restrict__ log_dt,
                            const float* __restrict__ log_A_real,
                            const float* __restrict__ A_imag,
                            const float* __restrict__ B_re, const float* __restrict__ B_im,
                            const float* __restrict__ C_re, const float* __restrict__ C_im,
                            float* __restrict__ a0, float* __restrict__ b0,
                            float* __restrict__ a1, float* __restrict__ b1,
                            float* __restrict__ pw) {
    int idx = blockIdx.x * blockDim.x + threadIdx.x;
    if (idx >= PARAM) return;
    int h = idx >> 6, n = idx & 63;
    float dt = expf(log_dt[h]);
    float Ar = -expf(log_A_real[idx]);
    float Ai = A_imag[idx];
    float er = expf(Ar * dt);
    float wr = er * cosf(Ai * dt);
    float wi = er * sinf(Ai * dt);
    float mr = wr - 1.0f, mi = wi;
    float den = Ar * Ar + Ai * Ai;
    float qr = (mr * Ar + mi * Ai) / den;
    float qi = (mi * Ar - mr * Ai) / den;
    float Br = B_re[idx], Bi = B_im[idx];
    float dBr = Br * qr - Bi * qi;
    float dBi = Br * qi + Bi * qr;
    float cr = C_re[idx], ci = C_im[idx];
    a0[idx] =  2.0f * (cr * dBr - ci * dBi);
    b0[idx] = -2.0f * (cr * dBi + ci * dBr);
    cr = C_re[PARAM + idx]; ci = C_im[PARAM + idx];
    a1[idx] =  2.0f * (cr * dBr - ci * dBi);
    b1[idx] = -2.0f * (cr * dBi + ci * dBr);
    float c = 1.f, s = 0.f;
    float* base = pw + (size_t)h * 65 * 128 + 2 * n;
    for (int d = 0; d <= 64; ++d) {
        *(float2*)(base + (size_t)d * 128) = float2{c, s};
        float nc = c * wr - s * wi;
        float ns = c * wi + s * wr;
        c = nc; s = ns;
    }
}

// ---------------------------------------------------------------------------
// Phase 1b: Toeplitz taps k[h][dir][d] = sum_n a*Re(w^d) + b*Im(w^d).
// ---------------------------------------------------------------------------
__global__ __launch_bounds__(128)
void ktap_kernel(const float* __restrict__ pw,
                 const float* __restrict__ a0, const float* __restrict__ b0,
                 const float* __restrict__ a1, const float* __restrict__ b1,
                 float* __restrict__ kt) {
    int h = blockIdx.x;
    int t = threadIdx.x;
    int dir = t >> 6, d = t & 63;
    const float* aa = dir ? a1 : a0;
    const float* bb = dir ? b1 : b0;
    const float* row = pw + (size_t)(h * 65 + d) * 128;
    float acc = 0.f;
    for (int n = 0; n < 64; ++n) {
        float2 v = *(const float2*)(row + 2 * n);
        acc = fmaf(aa[h * 64 + n], v.x, acc);
        acc = fmaf(bb[h * 64 + n], v.y, acc);
    }
    kt[((size_t)h * 2 + dir) * 64 + d] = acc;
}

// ---------------------------------------------------------------------------
// Phase 2: LayerNorm over channel dim H for each (b,l).  (unchanged)
// ---------------------------------------------------------------------------
__global__ __launch_bounds__(256)
void ln_kernel(const float* __restrict__ x, const float* __restrict__ lnw,
               const float* __restrict__ lnb, float* __restrict__ z) {
    int blk = blockIdx.x;
    int b  = blk / (Lq / 16);
    int l0 = (blk % (Lq / 16)) * 16;
    int tx = threadIdx.x & 15;
    int ty = threadIdx.x >> 4;
    const float* xb = x + (size_t)b * Hq * Lq;
    float s = 0.f, s2 = 0.f;
    for (int h = ty; h < Hq; h += 16) {
        float v = xb[h * Lq + l0 + tx];
        s += v; s2 += v * v;
    }
    __shared__ float rs_[16][17], r2_[16][17], mu_s[16], sg_s[16];
    rs_[ty][tx] = s; r2_[ty][tx] = s2;
    __syncthreads();
    if (ty == 0) {
        float a = 0.f, c = 0.f;
        #pragma unroll
        for (int i = 0; i < 16; ++i) { a += rs_[i][tx]; c += r2_[i][tx]; }
        float mu = a * (1.0f / Hq);
        float var = c * (1.0f / Hq) - mu * mu;
        mu_s[tx] = mu;
        sg_s[tx] = rsqrtf(var + 1e-5f);
    }
    __syncthreads();
    float mu = mu_s[tx], rs = sg_s[tx];
    float* zb = z + (size_t)b * Hq * Lq;
    for (int h = ty; h < Hq; h += 16) {
        float v = xb[h * Lq + l0 + tx];
        zb[h * Lq + l0 + tx] = (v - mu) * rs * lnw[h] + lnb[h];
    }
}

// ---------------------------------------------------------------------------
// delta GEMM (unchanged from round 3)
// ---------------------------------------------------------------------------
__global__ __launch_bounds__(256, 6)
void delta_kernel(const float* __restrict__ z, const float* __restrict__ pw,
                  float* __restrict__ buf) {
    __shared__ float Bs[64][68];
    int h = blockIdx.x, ct = blockIdx.y;
    int t = threadIdx.x;
    int dir = ct >> 1;
    int cc = t & 31, rb = (t >> 5) & 1, jg = t >> 6;
    int b = (ct & 1) * 2 + rb;
    const float* zb = z + ((size_t)b * Hq + h) * Lq;
    if (dir == 0) {
        #pragma unroll
        for (int f = 0; f < 4; ++f) {
            float4 v = *(const float4*)(zb + cc * 64 + 16 * jg + 4 * f);
            Bs[16*jg+4*f+0][rb*32+cc] = v.x;
            Bs[16*jg+4*f+1][rb*32+cc] = v.y;
            Bs[16*jg+4*f+2][rb*32+cc] = v.z;
            Bs[16*jg+4*f+3][rb*32+cc] = v.w;
        }
    } else {
        #pragma unroll
        for (int f = 0; f < 4; ++f) {
            float4 v = *(const float4*)(zb + 2044 - cc * 64 - 16 * jg - 4 * f);
            Bs[16*jg+4*f+3][rb*32+cc] = v.x;
            Bs[16*jg+4*f+2][rb*32+cc] = v.y;
            Bs[16*jg+4*f+1][rb*32+cc] = v.z;
            Bs[16*jg+4*f+0][rb*32+cc] = v.w;
        }
    }
    __syncthreads();
    int tx = t & 15, ty = t >> 4;
    float aR[4][4] = {}, aI[4][4] = {};
    const float* pwh = pw + (size_t)h * 65 * 128;
    #pragma unroll 4
    for (int kk = 0; kk < 64; ++kk) {
        int d = 63 - kk;
        const float4* pr = (const float4*)(pwh + (size_t)d * 128 + 8 * tx);
        float4 p0 = pr[0], p1 = pr[1];
        float4 bv = *(const float4*)&Bs[kk][4 * ty];
        float pc[4] = {p0.x, p0.z, p1.x, p1.z};
        float ps[4] = {p0.y, p0.w, p1.y, p1.w};
        #pragma unroll
        for (int rr = 0; rr < 4; ++rr) {
            #pragma unroll
            for (int q = 0; q < 4; ++q) {
                aR[rr][q] = fmaf(pc[rr], (&bv.x)[q], aR[rr][q]);
                aI[rr][q] = fmaf(ps[rr], (&bv.x)[q], aI[rr][q]);
            }
        }
    }
    #pragma unroll
    for (int q = 0; q < 4; ++q) {
        int colg = ct * 64 + 4 * ty + q;
        float* dst = buf + ((size_t)h * NCOL + colg) * 128 + 8 * tx;
        float4 v1, v2;
        v1.x = aR[0][q]; v1.y = aI[0][q]; v1.z = aR[1][q]; v1.w = aI[1][q];
        v2.x = aR[2][q]; v2.y = aI[2][q]; v2.z = aR[3][q]; v2.w = aI[3][q];
        *(float4*)dst = v1; *(float4*)(dst + 4) = v2;
    }
}

// ---------------------------------------------------------------------------
// inter-chunk scan (unchanged)
// ---------------------------------------------------------------------------
__global__ __launch_bounds__(256)
void cscan_kernel(const float* __restrict__ pw, float* __restrict__ buf) {
    int e = blockIdx.x * 4 + (threadIdx.x >> 6);
    int n = threadIdx.x & 63;
    int h = e >> 3, dir = (e >> 2) & 1, b = e & 3;
    float2 t64 = *(const float2*)(pw + (size_t)(h * 65 + 64) * 128 + 2 * n);
    float tc = t64.x, ts = t64.y;
    float sr = 0.f, si = 0.f;
    float2* p = (float2*)(buf + ((size_t)h * NCOL + dir * 128 + b * 32) * 128) + n;
    float2 d = p[0];
    for (int c = 0; c < NC; ++c) {
        float2 dn;
        if (c + 1 < NC) dn = p[(c + 1) * 64];
        float2 s; s.x = sr; s.y = si;
        p[c * 64] = s;
        float nr = fmaf(tc, sr, fmaf(-ts, si, d.x));
        float ni = fmaf(ts, sr, fmaf(tc, si, d.y));
        sr = nr; si = ni; d = dn;
    }
}

// ---------------------------------------------------------------------------
// Fused Y GEMM + activation. Block = (h, ctB) covering batches {2ctB, 2ctB+1},
// all 32 chunks, both dirs. dir1's physical position for l = 64c+i comes from
// dir1 row 63-i, chunk 31-c — routed through LDS. Epilogue writes
// u = gelu(y0 + y1 + D*z) directly.
// ---------------------------------------------------------------------------
template <int DIR>
__device__ __forceinline__ void y_phases(const float* __restrict__ zb0,
                                         const float* __restrict__ zb1,
                                         const float* __restrict__ pwh,
                                         const float* __restrict__ bufh,
                                         const float* __restrict__ ks,
                                         const float* __restrict__ as_,
                                         const float* __restrict__ bs_,
                                         float (*As)[68], float (*Bs)[68],
                                         int t, int ctB, float acc[4][4]) {
    int tx = t & 15, ty = t >> 4;
    int si = t & 63, sg = t >> 6;
    int cc = t & 31, rb = (t >> 5) & 1, kg = t >> 6;
    const float* zb = rb ? zb1 : zb0;
    const float* prow = pwh + (size_t)(si + ((DIR == 0) ? 1 : 0)) * 128;
    for (int p = 0; p < 6; ++p) {
        if (p < 2) {
            #pragma unroll
            for (int q = 0; q < 8; ++q) {
                int kk = 8 * sg + q;
                int j = 32 * p + kk;
                int idx = (DIR == 0) ? (si - j) : (si - j - 1);
                As[kk][si] = (idx >= 0) ? ks[idx] : 0.f;
            }
        } else {
            #pragma unroll
            for (int q = 0; q < 8; ++q) {
                int kk = 8 * sg + q;
                int m = 32 * (p - 2) + kk;
                int n = m >> 1;
                float2 v = *(const float2*)(prow + 2 * n);
                float av = as_[n], bv = bs_[n];
                As[kk][si] = ((m & 1) == 0) ? fmaf(av, v.x, bv * v.y)
                                            : fmaf(bv, v.x, -av * v.y);
            }
        }
        if (p < 2) {
            if (DIR == 0) {
                #pragma unroll
                for (int f = 0; f < 2; ++f) {
                    float4 v = *(const float4*)(zb + cc * 64 + 32 * p + 8 * kg + 4 * f);
                    Bs[8*kg+4*f+0][rb*32+cc] = v.x;
                    Bs[8*kg+4*f+1][rb*32+cc] = v.y;
                    Bs[8*kg+4*f+2][rb*32+cc] = v.z;
                    Bs[8*kg+4*f+3][rb*32+cc] = v.w;
                }
            } else {
                #pragma unroll
                for (int f = 0; f < 2; ++f) {
                    float4 v = *(const float4*)(zb + 2044 - cc * 64 - 32 * p - 8 * kg - 4 * f);
                    Bs[8*kg+4*f+3][rb*32+cc] = v.x;
                    Bs[8*kg+4*f+2][rb*32+cc] = v.y;
                    Bs[8*kg+4*f+1][rb*32+cc] = v.z;
                    Bs[8*kg+4*f+0][rb*32+cc] = v.w;
                }
            }
        } else {
            int colg = DIR * 128 + ctB * 64 + rb * 32 + cc;
            const float* src = bufh + (size_t)colg * 128 + 32 * (p - 2) + 8 * kg;
            float4 v0 = *(const float4*)src;
            float4 v1 = *(const float4*)(src + 4);
            #pragma unroll
            for (int e2 = 0; e2 < 4; ++e2) Bs[8*kg+e2][rb*32+cc]   = (&v0.x)[e2];
            #pragma unroll
            for (int e2 = 0; e2 < 4; ++e2) Bs[8*kg+4+e2][rb*32+cc] = (&v1.x)[e2];
        }
        __syncthreads();
        #pragma unroll 8
        for (int kk = 0; kk < 32; ++kk) {
            float4 av = *(const float4*)&As[kk][4 * tx];
            float4 bv = *(const float4*)&Bs[kk][4 * ty];
            #pragma unroll
            for (int ii = 0; ii < 4; ++ii) {
                float a = (&av.x)[ii];
                acc[ii][0] = fmaf(a, bv.x, acc[ii][0]);
                acc[ii][1] = fmaf(a, bv.y, acc[ii][1]);
                acc[ii][2] = fmaf(a, bv.z, acc[ii][2]);
                acc[ii][3] = fmaf(a, bv.w, acc[ii][3]);
            }
        }
        __syncthreads();
    }
}

__global__ __launch_bounds__(256, 4)
void yact_kernel(const float* __restrict__ z, const float* __restrict__ pw,
                 const float* __restrict__ a0, const float* __restrict__ b0,
                 const float* __restrict__ a1, const float* __restrict__ b1,
                 const float* __restrict__ kt, const float* __restrict__ buf,
                 const float* __restrict__ Dv, float* __restrict__ u) {
    __shared__ float sh[64 * 68];               // As | Bs, reused as S1[64][68]
    __shared__ float ks0[64], ks1[64], as0[64], bs0[64], as1[64], bs1[64];
    int h = blockIdx.x, ctB = blockIdx.y;
    int t = threadIdx.x;
    if (t < 64) {
        ks0[t] = kt[((size_t)h * 2 + 0) * 64 + t];
        ks1[t] = kt[((size_t)h * 2 + 1) * 64 + t];
        as0[t] = a0[h * 64 + t]; bs0[t] = b0[h * 64 + t];
        as1[t] = a1[h * 64 + t]; bs1[t] = b1[h * 64 + t];
    }
    __syncthreads();
    const float* zb0 = z + ((size_t)(2 * ctB) * Hq + h) * Lq;
    const float* zb1 = z + ((size_t)(2 * ctB + 1) * Hq + h) * Lq;
    const float* pwh = pw + (size_t)h * 65 * 128;
    const float* bufh = buf + (size_t)h * NCOL * 128;
    float (*As)[68] = (float(*)[68])sh;
    float (*Bs)[68] = (float(*)[68])(sh + 32 * 68);
    float acc0[4][4] = {}, acc1[4][4] = {};
    y_phases<0>(zb0, zb1, pwh, bufh, ks0, as0, bs0, As, Bs, t, ctB, acc0);
    y_phases<1>(zb0, zb1, pwh, bufh, ks1, as1, bs1, As, Bs, t, ctB, acc1);
    // stash acc1 transposed: S1[col][row] (loop left a trailing barrier)
    float (*S1)[68] = (float(*)[68])sh;
    int tx = t & 15, ty = t >> 4;
    #pragma unroll
    for (int q = 0; q < 4; ++q) {
        float4 v;
        v.x = acc1[0][q]; v.y = acc1[1][q]; v.z = acc1[2][q]; v.w = acc1[3][q];
        *(float4*)&S1[4 * ty + q][4 * tx] = v;
    }
    __syncthreads();
    float dv = Dv[h];
    #pragma unroll
    for (int q = 0; q < 4; ++q) {
        int coll = 4 * ty + q;
        int rb2 = coll >> 5, cc2 = coll & 31;
        int b = 2 * ctB + rb2;
        int colrev = rb2 * 32 + (31 - cc2);
        float4 w = *(const float4*)&S1[colrev][60 - 4 * tx]; // rows 63-i, i=4tx+ii
        size_t base = ((size_t)b * Hq + h) * Lq + cc2 * 64 + 4 * tx;
        float4 zr = *(const float4*)(z + base);
        float vv[4];
        vv[0] = acc0[0][q] + w.w + dv * zr.x;
        vv[1] = acc0[1][q] + w.z + dv * zr.y;
        vv[2] = acc0[2][q] + w.y + dv * zr.z;
        vv[3] = acc0[3][q] + w.x + dv * zr.w;
        #pragma unroll
        for (int i = 0; i < 4; ++i) {
            float v = vv[i];
            float tt = tanhf(0.7978845608028654f * (v + 0.044715f * v * v * v));
            vv[i] = 0.5f * v * (1.0f + tt);
        }
        float4 r; r.x = vv[0]; r.y = vv[1]; r.z = vv[2]; r.w = vv[3];
        *(float4*)(u + base) = r;
    }
}

// ---------------------------------------------------------------------------
// Phase 5: out = bias + x + W@u.
// 512 threads, tile 128(o) x 64(l), BK=32, double-buffered LDS,
// one barrier per K-tile; all inner-loop LDS reads aligned b128.
// ---------------------------------------------------------------------------
__global__ __launch_bounds__(512, 4)
void gemm_kernel(const float* __restrict__ u, const float* __restrict__ W,
                 const float* __restrict__ bias, const float* __restrict__ x,
                 float* __restrict__ out) {
    int l0 = blockIdx.x * 64;
    int o0 = blockIdx.y * 128;
    int b  = blockIdx.z;
    int tid = threadIdx.x;
    __shared__ float Ws[2][32][132];
    __shared__ float Us[2][32][68];
    const float* ub = u + (size_t)b * Hq * Lq;
    float acc[4][4] = {};
    int wo = tid >> 4, wl = tid & 15;          // microtile 4o x 4l
    int sj = tid & 31, so = tid >> 5;          // Ws staging: k=sj, o=so+16r
    int sl = tid & 63, sk = tid >> 6;          // Us staging: l=sl, k=4sk+r
    float wreg[8], ureg[4];
    #pragma unroll
    for (int r = 0; r < 8; ++r) wreg[r] = W[(size_t)(o0 + so + 16*r) * Hq + sj];
    #pragma unroll
    for (int r = 0; r < 4; ++r) ureg[r] = ub[(size_t)(4*sk + r) * Lq + l0 + sl];
    #pragma unroll
    for (int r = 0; r < 8; ++r) Ws[0][sj][so + 16*r] = wreg[r];
    #pragma unroll
    for (int r = 0; r < 4; ++r) Us[0][4*sk + r][sl] = ureg[r];
    __syncthreads();
    for (int t = 0; t < Hq / 32; ++t) {
        int cur = t & 1;
        if (t < 15) {
            int k0 = (t + 1) * 32;
            #pragma unroll
            for (int r = 0; r < 8; ++r)
                wreg[r] = W[(size_t)(o0 + so + 16*r) * Hq + k0 + sj];
            #pragma unroll
            for (int r = 0; r < 4; ++r)
                ureg[r] = ub[(size_t)(k0 + 4*sk + r) * Lq + l0 + sl];
        }
        #pragma unroll 8
        for (int j = 0; j < 32; ++j) {
            float4 av = *(const float4*)&Ws[cur][j][4 * wo];
            float4 bv = *(const float4*)&Us[cur][j][4 * wl];
            #pragma unroll
            for (int io = 0; io < 4; ++io) {
                float a = (&av.x)[io];
                acc[io][0] = fmaf(a, bv.x, acc[io][0]);
                acc[io][1] = fmaf(a, bv.y, acc[io][1]);
                acc[io][2] = fmaf(a, bv.z, acc[io][2]);
                acc[io][3] = fmaf(a, bv.w, acc[io][3]);
            }
        }
        if (t < 15) {
            int nxt = cur ^ 1;
            #pragma unroll
            for (int r = 0; r < 8; ++r) Ws[nxt][sj][so + 16*r] = wreg[r];
            #pragma unroll
            for (int r = 0; r < 4; ++r) Us[nxt][4*sk + r][sl] = ureg[r];
        }
        __syncthreads();
    }
    #pragma unroll
    for (int io = 0; io < 4; ++io) {
        int o = o0 + 4 * wo + io;
        float bo = bias[o];
        size_t base = ((size_t)b * Hq + o) * Lq + l0 + 4 * wl;
        const float4 xr = *(const float4*)(x + base);
        float4 r;
        r.x = acc[io][0] + bo + xr.x;
        r.y = acc[io][1] + bo + xr.y;
        r.z = acc[io][2] + bo + xr.z;
        r.w = acc[io][3] + bo + xr.w;
        *(float4*)(out + base) = r;
    }
}

// ---------------------------------------------------------------------------
extern "C" void kernel_launch(void* const* d_in, const int* in_sizes, int n_in,
                              void* d_out, int out_size, void* d_ws, size_t ws_size,
                              hipStream_t stream) {
    (void)in_sizes; (void)n_in; (void)out_size; (void)ws_size;
    const float* x          = (const float*)d_in[0];
    const float* ln_w       = (const float*)d_in[1];
    const float* ln_b       = (const float*)d_in[2];
    const float* log_dt     = (const float*)d_in[3];
    const float* log_A_real = (const float*)d_in[4];
    const float* A_imag     = (const float*)d_in[5];
    const float* B_re       = (const float*)d_in[6];
    const float* B_im       = (const float*)d_in[7];
    const float* C_re       = (const float*)d_in[8];
    const float* C_im       = (const float*)d_in[9];
    const float* Dv         = (const float*)d_in[10];
    const float* W          = (const float*)d_in[11];
    const float* b_out      = (const float*)d_in[12];
    float* out = (float*)d_out;
    float* ws  = (float*)d_ws;

    const size_t BHL = (size_t)Bq * Hq * Lq;
    float* a0  = ws;
    float* b0  = ws + (size_t)PARAM;
    float* a1  = ws + 2 * (size_t)PARAM;
    float* b1  = ws + 3 * (size_t)PARAM;
    float* kt  = ws + 4 * (size_t)PARAM;
    float* pw  = ws + 6 * (size_t)PARAM;           // 512*65*128 = 130*PARAM
    float* z   = ws + 136 * (size_t)PARAM;
    float* u   = z  + BHL;                         // gelu output
    float* buf = u + BHL;                          // 512*256*128 = 67 MB

    prep_kernel<<<PARAM / 256, 256, 0, stream>>>(log_dt, log_A_real, A_imag,
                                                 B_re, B_im, C_re, C_im,
                                                 a0, b0, a1, b1, pw);
    ln_kernel<<<Bq * (Lq / 16), 256, 0, stream>>>(x, ln_w, ln_b, z);
    ktap_kernel<<<Hq, 128, 0, stream>>>(pw, a0, b0, a1, b1, kt);
    delta_kernel<<<dim3(Hq, 4), 256, 0, stream>>>(z, pw, buf);
    cscan_kernel<<<Bq * Hq * 2 / 4, 256, 0, stream>>>(pw, buf);
    yact_kernel<<<dim3(Hq, 2), 256, 0, stream>>>(z, pw, a0, b0, a1, b1,
                                                 kt, buf, Dv, u);
    gemm_kernel<<<dim3(Lq / 64, Hq / 128, Bq), 512, 0, stream>>>(u, W, b_out, x, out);
}